// Round 13
// baseline (138.288 us; speedup 1.0000x reference)
//
#include <hip/hip_runtime.h>
#include <math.h>

// DTM weighted-quantile kernel, v3: Illinois regula-falsi bracketing.
// One wave64 per (b, n) output; M=2048 -> 32 contiguous elems/lane in regs.
//
// r8/r10 evidence: v1 (31 bisect iters) 82.4us; v2 (~15 iters, -25% VALU work)
// 79.5us => NOT issue-bound; floor = ~16 serial round trips per wave, each a
// 6-deep shfl_xor reduce chain (~200+cy) + uniform branch. v3 halves the
// round trips: interpolate on the empirical CDF (Illinois-safeguarded) to
// isolate the quantile bracket in ~5-8 counts, then exact extraction (same as
// v2) keeps the result bit-exact w.r.t. the selection semantics.

#define M_POINTS 2048
#define PER_LANE 32  // M_POINTS / 64
#define M0 0.3f

__device__ __forceinline__ float wave_reduce_sum(float v) {
    #pragma unroll
    for (int off = 1; off < 64; off <<= 1)
        v += __shfl_xor(v, off, 64);
    return v;
}
__device__ __forceinline__ float wave_reduce_max(float v) {
    #pragma unroll
    for (int off = 1; off < 64; off <<= 1)
        v = fmaxf(v, __shfl_xor(v, off, 64));
    return v;
}
__device__ __forceinline__ float wave_reduce_min(float v) {
    #pragma unroll
    for (int off = 1; off < 64; off <<= 1)
        v = fminf(v, __shfl_xor(v, off, 64));
    return v;
}

__global__ __launch_bounds__(256) void dtm_kernel(
    const float* __restrict__ inputs,   // [B, M, 2]
    const float* __restrict__ weight,   // [B, M]
    const float* __restrict__ grid,     // [N, 2]
    float* __restrict__ out,            // [B, N]  (f32)
    int B, int N)
{
    const int lane = threadIdx.x & 63;
    const int gwave = blockIdx.x * (blockDim.x >> 6) + (threadIdx.x >> 6);
    if (gwave >= B * N) return;           // wave-uniform exit
    const int b = gwave / N;
    const int n = gwave - b * N;

    const float gx = grid[2 * n];
    const float gy = grid[2 * n + 1];

    const float* __restrict__ inb = inputs + (size_t)b * M_POINTS * 2;
    const float* __restrict__ wb  = weight + (size_t)b * M_POINTS;

    // Contiguous 32 elements per lane -> float4 staging.
    const int base = lane * PER_LANE;
    const float4* __restrict__ xyv = reinterpret_cast<const float4*>(inb + 2 * base);
    const float4* __restrict__ wv  = reinterpret_cast<const float4*>(wb + base);

    float d2[PER_LANE], w[PER_LANE];
    float wsum_local = 0.0f, vmax_local = 0.0f;
    #pragma unroll
    for (int q = 0; q < PER_LANE / 4; ++q) {
        const float4 wq = wv[q];
        const float4 a  = xyv[2 * q];       // x0 y0 x1 y1
        const float4 c4 = xyv[2 * q + 1];   // x2 y2 x3 y3
        float dx, dy;
        dx = a.x  - gx; dy = a.y  - gy; d2[4*q+0] = fmaf(dx, dx, dy * dy);
        dx = a.z  - gx; dy = a.w  - gy; d2[4*q+1] = fmaf(dx, dx, dy * dy);
        dx = c4.x - gx; dy = c4.y - gy; d2[4*q+2] = fmaf(dx, dx, dy * dy);
        dx = c4.z - gx; dy = c4.w - gy; d2[4*q+3] = fmaf(dx, dx, dy * dy);
        w[4*q+0] = wq.x; w[4*q+1] = wq.y; w[4*q+2] = wq.z; w[4*q+3] = wq.w;
        wsum_local += wq.x + wq.y + wq.z + wq.w;
        vmax_local = fmaxf(vmax_local, fmaxf(fmaxf(d2[4*q+0], d2[4*q+1]),
                                             fmaxf(d2[4*q+2], d2[4*q+3])));
    }
    const float total = wave_reduce_sum(wsum_local);
    const float bound = M0 * total;

    // Phase 1: Illinois regula falsi on F(v) = sum(w | d2<=v) - bound.
    // Bracket invariant: wlo = F+bound at vlo < bound <= whi at vhi.
    float vlo = 0.0f, wlo = 0.0f;                 // d2 >= 0 always
    float vhi = wave_reduce_max(vmax_local), whi = total;
    float flo_i = wlo - bound, fhi_i = whi - bound;  // interp copies (Illinois)
    int last_side = 0;                             // +1 = hi moved, -1 = lo moved
    #pragma unroll 1
    for (int it = 0; it < 40; ++it) {
        if (whi - wlo <= 0.75f) break;             // bracket ~<=2 elements
        // Illinois interpolation; fall back to bisection if degenerate.
        float vmid = (vlo * fhi_i - vhi * flo_i) / (fhi_i - flo_i);
        if (!(vmid > vlo && vmid < vhi))
            vmid = 0.5f * (vlo + vhi);
        if (!(vmid > vlo && vmid < vhi)) break;    // adjacent floats (ties)
        float c = 0.0f;
        #pragma unroll
        for (int j = 0; j < PER_LANE; ++j)
            c += (d2[j] <= vmid) ? w[j] : 0.0f;
        c = wave_reduce_sum(c);
        if (c >= bound) {                          // hi side replaced
            vhi = vmid; whi = c; fhi_i = c - bound;
            if (last_side == +1) flo_i *= 0.5f;    // stale lo -> Illinois halve
            last_side = +1;
        } else {                                   // lo side replaced
            vlo = vmid; wlo = c; flo_i = c - bound;
            if (last_side == -1) fhi_i *= 0.5f;    // stale hi -> Illinois halve
            last_side = -1;
        }
    }

    // Phase 2: exact extraction - ascending distinct values above vlo.
    float r2 = vhi, W = wlo;
    #pragma unroll 1
    for (int step = 0; step < 64; ++step) {
        float m = __builtin_inff();
        #pragma unroll
        for (int j = 0; j < PER_LANE; ++j)
            m = fminf(m, (d2[j] > vlo) ? d2[j] : __builtin_inff());
        m = wave_reduce_min(m);                    // smallest value > vlo
        float c = 0.0f;
        #pragma unroll
        for (int j = 0; j < PER_LANE; ++j)
            c += (d2[j] <= m) ? w[j] : 0.0f;
        c = wave_reduce_sum(c);
        if (c >= bound) { r2 = m; W = wlo; break; }  // wlo = cnt(values < m)
        vlo = m; wlo = c;
    }

    // Phase 3: S = sum_{d2 < r2} w*d2.
    float S = 0.0f;
    #pragma unroll
    for (int j = 0; j < PER_LANE; ++j)
        if (d2[j] < r2) S = fmaf(w[j], d2[j], S);
    S = wave_reduce_sum(S);

    const float margin = fmaxf(bound - W, 0.0f);   // clamp FP-noise sign flip
    const float val = fmaxf(fmaf(r2, margin, S), 0.0f);
    if (lane == 0) out[gwave] = sqrtf(val / bound);
}

extern "C" void kernel_launch(void* const* d_in, const int* in_sizes, int n_in,
                              void* d_out, int out_size, void* d_ws, size_t ws_size,
                              hipStream_t stream) {
    const float* inputs = (const float*)d_in[0];   // [B, M, 2]
    const float* weight = (const float*)d_in[1];   // [B, M]
    const float* grid   = (const float*)d_in[2];   // [N, 2]
    float* out = (float*)d_out;                    // [B, N] f32

    const int N = in_sizes[2] / 2;                 // 6561
    const int B = out_size / N;                    // 2
    // M hard-wired to 2048 (PER_LANE*64).

    const int total_waves = B * N;                 // 13122
    const int waves_per_block = 256 / 64;
    const int blocks = (total_waves + waves_per_block - 1) / waves_per_block;

    dtm_kernel<<<blocks, 256, 0, stream>>>(inputs, weight, grid, out, B, N);
}